// Round 22
// baseline (386.259 us; speedup 1.0000x reference)
//
#include <hip/hip_runtime.h>
#include <math.h>

#define CDIM 256
#define HD 8
#define DD 32
#define NT 3
#define ET 5
#define QWC (ET * CDIM)     // 1280

typedef unsigned short u16;
typedef __attribute__((ext_vector_type(8))) short s16x8;
typedef __attribute__((ext_vector_type(4))) float f32x4;

__device__ __forceinline__ float b2f(u16 u) { return __uint_as_float(((unsigned)u) << 16); }
__device__ __forceinline__ u16 f2b(float x) {
    unsigned u = __float_as_uint(x);
    return (u16)((u + 0x7FFF + ((u >> 16) & 1)) >> 16);
}

// ================= node-type buckets (atomic-free, stable) =================
__global__ void bhist_k(const int* __restrict__ ntype, int N, int nblk, int* __restrict__ bcnt) {
    __shared__ int wc[4][NT];
    int b = blockIdx.x, tid = threadIdx.x, lane = tid & 63, w = tid >> 6;
    int i = b * 256 + tid;
    int t = (i < N) ? ntype[i] : -1;
#pragma unroll
    for (int r = 0; r < NT; ++r) {
        unsigned long long m = __ballot(t == r);
        if (lane == 0) wc[w][r] = __popcll(m);
    }
    __syncthreads();
    if (tid < NT) bcnt[tid * nblk + b] = wc[0][tid] + wc[1][tid] + wc[2][tid] + wc[3][tid];
}

__global__ void bscan_k(const int* __restrict__ bcnt, int* __restrict__ base,
                        int* __restrict__ off, int total, int nblk, int N) {
    __shared__ int s[1024];
    int t = threadIdx.x;
    int v = (t < total) ? bcnt[t] : 0;
    s[t] = v; __syncthreads();
    for (int o = 1; o < 1024; o <<= 1) {
        int u = (t >= o) ? s[t - o] : 0; __syncthreads();
        s[t] += u; __syncthreads();
    }
    if (t < total) base[t] = s[t] - v;
    if (t < NT) off[t] = s[t * nblk] - bcnt[t * nblk];
    if (t == NT) off[NT] = N;
}

__global__ void bscatter_k(const int* __restrict__ ntype, int N, int nblk,
                           const int* __restrict__ base, int* __restrict__ perm) {
    __shared__ int wc[4][NT];
    __shared__ int woff[4][NT];
    int b = blockIdx.x, tid = threadIdx.x, lane = tid & 63, w = tid >> 6;
    int i = b * 256 + tid;
    int t = (i < N) ? ntype[i] : -1;
    unsigned long long mlt = (1ULL << lane) - 1;
    int rank = 0;
#pragma unroll
    for (int r = 0; r < NT; ++r) {
        unsigned long long m = __ballot(t == r);
        if (lane == 0) wc[w][r] = __popcll(m);
        if (t == r) rank = __popcll(m & mlt);
    }
    __syncthreads();
    if (tid == 0) {
#pragma unroll
        for (int r = 0; r < NT; ++r) {
            int a = 0;
#pragma unroll
            for (int w0 = 0; w0 < 4; ++w0) { woff[w0][r] = a; a += wc[w0][r]; }
        }
    }
    __syncthreads();
    if (t >= 0) perm[base[t * nblk + b] + woff[w][t] + rank] = i;
}

// ================= edge counting sort by key = dst*ET + etype =================
__global__ void ehist_k(const int* __restrict__ dst, const int* __restrict__ etype, int E,
                        int* __restrict__ khist) {
    int i = blockIdx.x * 256 + threadIdx.x;
    if (i < E) atomicAdd(&khist[dst[i] * ET + etype[i]], 1);
}

__global__ void kscan1_k(const int* __restrict__ khist, int* __restrict__ kscan,
                         int* __restrict__ bsum, int KEYS) {
    __shared__ int s[256];
    int b = blockIdx.x, t = threadIdx.x, i = b * 256 + t;
    int v = (i < KEYS) ? khist[i] : 0;
    s[t] = v; __syncthreads();
    for (int o = 1; o < 256; o <<= 1) {
        int u = (t >= o) ? s[t - o] : 0; __syncthreads();
        s[t] += u; __syncthreads();
    }
    if (i < KEYS) kscan[i] = s[t] - v;
    if (t == 255) bsum[b] = s[t];
}

__global__ void kscan2_k(int* __restrict__ bsum, int NB) {
    __shared__ int s[1024];
    int t = threadIdx.x;
    int v = (t < NB) ? bsum[t] : 0;
    s[t] = v; __syncthreads();
    for (int o = 1; o < 1024; o <<= 1) {
        int u = (t >= o) ? s[t - o] : 0; __syncthreads();
        s[t] += u; __syncthreads();
    }
    if (t < NB) bsum[t] = s[t] - v;
}

// merged: kscan += bsum, and rowptr = result (+ rowptr[KEYS] = E)
__global__ void kscan3r_k(int* __restrict__ kscan, const int* __restrict__ bsum,
                          int* __restrict__ rowptr, int KEYS, int E) {
    int i = blockIdx.x * 256 + threadIdx.x;
    if (i < KEYS) {
        int v = kscan[i] + bsum[blockIdx.x];
        kscan[i] = v;
        rowptr[i] = v;
    }
    if (i == 0) rowptr[KEYS] = E;
}

// epay packs (etype << 24) | src
__global__ void escatter_k(const int* __restrict__ src, const int* __restrict__ dst,
                           const int* __restrict__ etype, int E,
                           int* __restrict__ kscan, int* __restrict__ epay) {
    int e = blockIdx.x * 256 + threadIdx.x;
    if (e < E) {
        int et = etype[e];
        int pos = atomicAdd(&kscan[dst[e] * ET + et], 1);
        epay[pos] = (et << 24) | src[e];
    }
}

// ================= fp32 -> bf16 copy (x -> xb) =================
__global__ void f2bv_k(const float* __restrict__ in, u16* __restrict__ out, size_t n4) {
    size_t i = (size_t)blockIdx.x * 256 + threadIdx.x;
    if (i >= n4) return;
    float4 v = ((const float4*)in)[i];
    ushort4 o; o.x = f2b(v.x); o.y = f2b(v.y); o.z = f2b(v.z); o.w = f2b(v.w);
    ((ushort4*)out)[i] = o;
}

// ================= Wk|Wv [t][k][c] f32 -> Wtb[z][c][k] bf16 (z: 0..NT-1 = Wk, NT..2NT-1 = Wv)
__global__ __launch_bounds__(256) void wconv2_k(const float* __restrict__ Wk,
                                                const float* __restrict__ Wv,
                                                u16* __restrict__ Wtb) {
    __shared__ u16 s[64][72];
    int k0 = blockIdx.x * 64, c0 = blockIdx.y * 64, z = blockIdx.z;
    const float* Wp = (z < NT) ? (Wk + (size_t)z * CDIM * CDIM)
                               : (Wv + (size_t)(z - NT) * CDIM * CDIM);
    int r = threadIdx.x >> 2, q = (threadIdx.x & 3) * 16;
#pragma unroll
    for (int m = 0; m < 16; m += 4) {
        float4 v = *(const float4*)(Wp + (size_t)(k0 + r) * CDIM + c0 + q + m);
        s[r][q + m + 0] = f2b(v.x); s[r][q + m + 1] = f2b(v.y);
        s[r][q + m + 2] = f2b(v.z); s[r][q + m + 3] = f2b(v.w);
    }
    __syncthreads();
    int c = threadIdx.x >> 2, kq = (threadIdx.x & 3) * 16;
    u16* op = Wtb + ((size_t)z * CDIM + c0 + c) * CDIM + k0 + kq;
#pragma unroll
    for (int m = 0; m < 16; m += 4) {
        ushort4 o;
        o.x = s[kq + m + 0][c]; o.y = s[kq + m + 1][c];
        o.z = s[kq + m + 2][c]; o.w = s[kq + m + 3][c];
        *(ushort4*)(op + m) = o;
    }
}

// ===== merged folds. y=0: qf_b[t][et*256+h*32+m][c] = sum_f Wq[t][c][h32+f]*Ratt[et,h,m,f]
//                    y=1: af_b[t][col][et*256+h*32+f] = sum_m Rmsg[et,h,f,m]*Wa[t][h32+m][col]
__global__ __launch_bounds__(256) void rfold_k(const float* __restrict__ Wq,
                                               const float* __restrict__ Ratt,
                                               u16* __restrict__ qf_b,
                                               const float* __restrict__ Wa,
                                               const float* __restrict__ Rmsg,
                                               u16* __restrict__ af_b) {
    __shared__ float Rs[DD][DD];
    int b = blockIdx.x;
    int t = b / (ET * HD);
    int eh = b % (ET * HD);
    int et = eh >> 3, h = eh & 7;
    int tid = threadIdx.x;

    if (blockIdx.y == 0) {
        float4 rv = ((const float4*)(Ratt + (size_t)eh * (DD * DD)))[tid];
        int r = tid >> 3, c4 = (tid & 7) * 4;
        Rs[r][c4 + 0] = rv.x; Rs[r][c4 + 1] = rv.y;
        Rs[r][c4 + 2] = rv.z; Rs[r][c4 + 3] = rv.w;   // Rs[m][f]
        __syncthreads();

        int c = tid;
        const float* wr = Wq + (size_t)t * (CDIM * CDIM) + (size_t)c * CDIM + h * DD;
        float wrow[DD];
#pragma unroll
        for (int f = 0; f < DD; f += 4) {
            float4 v = *(const float4*)(wr + f);
            wrow[f] = v.x; wrow[f + 1] = v.y; wrow[f + 2] = v.z; wrow[f + 3] = v.w;
        }
        for (int m = 0; m < DD; ++m) {
            float acc = 0.f;
#pragma unroll
            for (int f = 0; f < DD; ++f) acc += wrow[f] * Rs[m][f];
            qf_b[((size_t)t * QWC + et * 256 + h * 32 + m) * CDIM + c] = f2b(acc);
        }
    } else {
        float4 rv = ((const float4*)(Rmsg + (size_t)eh * (DD * DD)))[tid];
        int r = tid >> 3, c4 = (tid & 7) * 4;
        Rs[r][c4 + 0] = rv.x; Rs[r][c4 + 1] = rv.y;
        Rs[r][c4 + 2] = rv.z; Rs[r][c4 + 3] = rv.w;   // Rs[f][m]
        __syncthreads();

        int col = tid;
        float wcol[DD];
#pragma unroll
        for (int m = 0; m < DD; ++m)
            wcol[m] = Wa[(size_t)t * (CDIM * CDIM) + (size_t)(h * 32 + m) * CDIM + col];

        u16* op = af_b + ((size_t)t * CDIM + col) * QWC + et * 256 + h * 32;
        for (int f = 0; f < DD; ++f) {
            float acc = 0.f;
#pragma unroll
            for (int m = 0; m < DD; ++m) acc += Rs[f][m] * wcol[m];
            op[f] = f2b(acc);
        }
    }
}

// ================= fused projection GEMM: [k|v|qw] = xb @ {Wk,Wv,Wq*Ratt} =================
// XCD-grouped 1D grid; 64x128 block tile; BK=32, [..][40] LDS layout.
__global__ __launch_bounds__(256) void gemmall_k(
    const u16* __restrict__ xb, const u16* __restrict__ wtb, const u16* __restrict__ qf_b,
    u16* __restrict__ kb, u16* __restrict__ vb, u16* __restrict__ qwsv,
    const int* __restrict__ perm, const int* __restrict__ off, int N, int bpt, int npanel)
{
    __shared__ u16 As[64][40];
    __shared__ u16 Bs[128][40];
    __shared__ int ridx[64];

    int bid = blockIdx.x;
    int xcd = bid & 7;
    int rr_ = bid >> 3;
    int g = rr_ / 14, bx = rr_ % 14;
    int p = g * 8 + xcd;
    if (p >= npanel) return;
    int t = p / bpt, bi = p % bpt;

    int i0 = off[t] + bi * 64, iend = off[t + 1];
    if (i0 >= iend) return;
    int tid = threadIdx.x;

    u16* out; int ostr, oc0; const u16* bslab;
    const size_t CC = (size_t)CDIM * CDIM;
    if (bx < 2)      { out = kb;   ostr = CDIM; oc0 = bx * 128;       bslab = wtb + (size_t)t * CC; }
    else if (bx < 4) { out = vb;   ostr = CDIM; oc0 = (bx - 2) * 128; bslab = wtb + (size_t)(NT + t) * CC; }
    else             { out = qwsv; ostr = QWC;  oc0 = (bx - 4) * 128; bslab = qf_b + (size_t)t * QWC * CDIM; }

    if (tid < 64) ridx[tid] = (i0 + tid < iend) ? perm[i0 + tid] : -1;
    __syncthreads();

    int sr = tid >> 2, sq = (tid & 3) * 8;     // A staging: 4 thr/row, 16B each
    int srB = tid >> 1, sqB = (tid & 1) * 16;  // B staging: 2 thr/row, 32B each
    int ar = ridx[sr];
    const u16* asrc = xb + (size_t)(ar < 0 ? 0 : ar) * CDIM + sq;
    const u16* bsrc = bslab + (size_t)(oc0 + srB) * CDIM + sqB;

    int lane = tid & 63, wid = tid >> 6;
    int wr = wid >> 1, wc = wid & 1;
    int l15 = lane & 15, lk = (lane >> 4) * 8;

    f32x4 acc[2][4];
#pragma unroll
    for (int mi = 0; mi < 2; ++mi)
#pragma unroll
        for (int j = 0; j < 4; ++j)
            acc[mi][j] = (f32x4){0.f, 0.f, 0.f, 0.f};

    uint4 apre = make_uint4(0, 0, 0, 0);
    if (ar >= 0) apre = *(const uint4*)(asrc);
    uint4 bp0 = *(const uint4*)(bsrc);
    uint4 bp1 = *(const uint4*)(bsrc + 8);

    for (int k0 = 0; k0 < CDIM; k0 += 32) {
        __syncthreads();
        *(uint4*)&As[sr][sq] = apre;
        *(uint4*)&Bs[srB][sqB] = bp0;
        *(uint4*)&Bs[srB][sqB + 8] = bp1;
        __syncthreads();

        if (k0 + 32 < CDIM) {
            if (ar >= 0) apre = *(const uint4*)(asrc + k0 + 32);
            bp0 = *(const uint4*)(bsrc + k0 + 32);
            bp1 = *(const uint4*)(bsrc + k0 + 40);
        }

        s16x8 af0 = *(const s16x8*)&As[wr * 32 + l15][lk];
        s16x8 af1 = *(const s16x8*)&As[wr * 32 + 16 + l15][lk];
#pragma unroll
        for (int j = 0; j < 4; ++j) {
            s16x8 bf = *(const s16x8*)&Bs[wc * 64 + j * 16 + l15][lk];
            acc[0][j] = __builtin_amdgcn_mfma_f32_16x16x32_bf16(af0, bf, acc[0][j], 0, 0, 0);
            acc[1][j] = __builtin_amdgcn_mfma_f32_16x16x32_bf16(af1, bf, acc[1][j], 0, 0, 0);
        }
    }

    int rbase = wr * 32 + (lane >> 4) * 4;
#pragma unroll
    for (int mi = 0; mi < 2; ++mi) {
#pragma unroll
        for (int r = 0; r < 4; ++r) {
            int node = ridx[rbase + mi * 16 + r];
            if (node < 0) continue;
            size_t b0 = (size_t)node * ostr + oc0 + wc * 64 + l15;
#pragma unroll
            for (int j = 0; j < 4; ++j)
                out[b0 + j * 16] = f2b(acc[mi][j][r]);
        }
    }
}

// ================= out GEMM v6: out = svn @ af_b (K=1280), 64x64 tiles, dbuf LDS ======
// 4 col-tiles per row-panel, XCD-grouped. Double-buffered A staging: ONE barrier per
// 64-k chunk (issue loads -> barrier -> compute As[cur] -> write As[cur^1]).
// B fragments direct from L2-resident af_b.
__global__ __launch_bounds__(256) void outgemm_k(
    const u16* __restrict__ svn, const u16* __restrict__ af_b, float* __restrict__ out,
    const int* __restrict__ perm, const int* __restrict__ off, int N, int bpt, int npanel,
    const float* __restrict__ x, const float* __restrict__ skip)
{
    __shared__ u16 As[2][64][68];
    __shared__ int ridx[64];

    int bid = blockIdx.x;
    int xcd = bid & 7;
    int rr_ = bid >> 3;
    int g = rr_ / 4, cx = rr_ % 4;
    int p = g * 8 + xcd;
    if (p >= npanel) return;
    int t = p / bpt, bi = p % bpt;
    int i0 = off[t] + bi * 64, iend = off[t + 1];
    if (i0 >= iend) return;
    int tid = threadIdx.x;
    if (tid < 64) ridx[tid] = (i0 + tid < iend) ? perm[i0 + tid] : -1;
    __syncthreads();

    int lane = tid & 63, y = tid >> 6;     // wave y owns out cols cx*64 + y*16 .. +16
    int l15 = lane & 15, lq = lane >> 4;
    int lk = lq * 8;
    int colb = cx * 64 + y * 16;

    int sr = tid >> 2, sc = (tid & 3) * 16;
    int ar = ridx[sr];
    const u16* asrc = svn + (size_t)(ar < 0 ? 0 : ar) * QWC + sc;
    const u16* brow = af_b + ((size_t)t * CDIM + colb + l15) * QWC;

    f32x4 acc[4];
#pragma unroll
    for (int mi = 0; mi < 4; ++mi) acc[mi] = (f32x4){0.f, 0.f, 0.f, 0.f};

    uint4 a0 = make_uint4(0, 0, 0, 0), a1 = make_uint4(0, 0, 0, 0);
    if (ar >= 0) {
        a0 = *(const uint4*)(asrc);
        a1 = *(const uint4*)(asrc + 8);
    }
    *(uint4*)&As[0][sr][sc] = a0;
    *(uint4*)&As[0][sr][sc + 8] = a1;

    s16x8 bf0 = *(const s16x8*)(brow + lk);
    s16x8 bf1 = *(const s16x8*)(brow + 32 + lk);

    for (int kc = 0; kc < 20; ++kc) {
        int cur = kc & 1;
        s16x8 b0c = bf0, b1c = bf1;
        if (kc + 1 < 20) {
            int ko = (kc + 1) * 64;
            if (ar >= 0) {
                a0 = *(const uint4*)(asrc + ko);
                a1 = *(const uint4*)(asrc + ko + 8);
            }
            bf0 = *(const s16x8*)(brow + ko + lk);
            bf1 = *(const s16x8*)(brow + ko + 32 + lk);
        }
        __syncthreads();   // all waves' As[cur] writes (prev iter) complete; prev reads of As[cur^1] done

#pragma unroll
        for (int mi = 0; mi < 4; ++mi) {
            s16x8 af0 = *(const s16x8*)&As[cur][mi * 16 + l15][lk];
            s16x8 af1 = *(const s16x8*)&As[cur][mi * 16 + l15][32 + lk];
            acc[mi] = __builtin_amdgcn_mfma_f32_16x16x32_bf16(af0, b0c, acc[mi], 0, 0, 0);
            acc[mi] = __builtin_amdgcn_mfma_f32_16x16x32_bf16(af1, b1c, acc[mi], 0, 0, 0);
        }

        if (kc + 1 < 20) {
            *(uint4*)&As[cur ^ 1][sr][sc] = a0;
            *(uint4*)&As[cur ^ 1][sr][sc + 8] = a1;
        }
    }

    float alpha = 1.f / (1.f + __expf(-skip[t]));
    float beta = 1.f - alpha;
#pragma unroll
    for (int mi = 0; mi < 4; ++mi) {
#pragma unroll
        for (int r = 0; r < 4; ++r) {
            int node = ridx[mi * 16 + lq * 4 + r];
            if (node < 0) continue;
            size_t b0 = (size_t)node * CDIM + colb + l15;
            out[b0] = acc[mi][r] * alpha + x[b0] * beta;
        }
    }
}

// ================= gather v3: one wave per dst; single merged edge loop (sorted by et),
// 2-deep prefetch, uniform-branch segment transitions, svn in-place over qw ============
__global__ __launch_bounds__(256) void gather3_k(
    const u16* __restrict__ kb, const u16* __restrict__ vb, u16* __restrict__ qwsv,
    const float* __restrict__ pri, const int* __restrict__ rowptr, const int* __restrict__ epay,
    int N)
{
    int d = (blockIdx.x * 256 + threadIdx.x) >> 6;
    if (d >= N) return;
    int lane = threadIdx.x & 63, h = lane >> 3;
    const float rsD = 0.17677669529663687f;
    size_t rowb = (size_t)d * QWC + lane * 4;

    ushort4 qu0 = *(const ushort4*)(qwsv + rowb);
    ushort4 qu1 = *(const ushort4*)(qwsv + rowb + 256);
    ushort4 qu2 = *(const ushort4*)(qwsv + rowb + 512);
    ushort4 qu3 = *(const ushort4*)(qwsv + rowb + 768);
    ushort4 qu4 = *(const ushort4*)(qwsv + rowb + 1024);

    int p0 = __builtin_amdgcn_readfirstlane(rowptr[d * ET]);
    int p1 = __builtin_amdgcn_readfirstlane(rowptr[d * ET + ET]);

    float Sv0[4] = {0,0,0,0}, Sv1[4] = {0,0,0,0}, Sv2[4] = {0,0,0,0};
    float Sv3[4] = {0,0,0,0}, Sv4[4] = {0,0,0,0};
    float a0 = 0.f, a1 = 0.f, a2 = 0.f, a3 = 0.f, dsum = 0.f;
    int cur_et = -1;
    float cq0 = 0.f, cq1 = 0.f, cq2 = 0.f, cq3 = 0.f, cpf = 0.f;

    int payc = 0; ushort4 kuc = {0,0,0,0}, vuc = {0,0,0,0};
    if (p0 < p1) {
        payc = epay[p0];
        int s = payc & 0xFFFFFF;
        kuc = *(const ushort4*)(kb + (size_t)s * CDIM + lane * 4);
        vuc = *(const ushort4*)(vb + (size_t)s * CDIM + lane * 4);
    }

    for (int p = p0; p < p1; ++p) {
        int payn = 0; ushort4 kun = {0,0,0,0}, vun = {0,0,0,0};
        if (p + 1 < p1) {
            payn = epay[p + 1];
            int sn = payn & 0xFFFFFF;
            kun = *(const ushort4*)(kb + (size_t)sn * CDIM + lane * 4);
            vun = *(const ushort4*)(vb + (size_t)sn * CDIM + lane * 4);
        }
        int et = __builtin_amdgcn_readfirstlane(payc) >> 24;
        if (et != cur_et) {
            switch (cur_et) {
                case 0: Sv0[0]=a0; Sv0[1]=a1; Sv0[2]=a2; Sv0[3]=a3; break;
                case 1: Sv1[0]=a0; Sv1[1]=a1; Sv1[2]=a2; Sv1[3]=a3; break;
                case 2: Sv2[0]=a0; Sv2[1]=a1; Sv2[2]=a2; Sv2[3]=a3; break;
                case 3: Sv3[0]=a0; Sv3[1]=a1; Sv3[2]=a2; Sv3[3]=a3; break;
                default: break;
            }
            a0 = a1 = a2 = a3 = 0.f;
            cur_et = et;
            ushort4 q = (et == 0) ? qu0 : (et == 1) ? qu1 : (et == 2) ? qu2
                       : (et == 3) ? qu3 : qu4;
            cq0 = b2f(q.x); cq1 = b2f(q.y); cq2 = b2f(q.z); cq3 = b2f(q.w);
            cpf = pri[et * HD + h] * rsD;
        }
        float t = b2f(kuc.x) * cq0 + b2f(kuc.y) * cq1 + b2f(kuc.z) * cq2 + b2f(kuc.w) * cq3;
        t += __shfl_xor(t, 1, 8);
        t += __shfl_xor(t, 2, 8);
        t += __shfl_xor(t, 4, 8);
        float ex = __expf(t * cpf);
        a0 += ex * b2f(vuc.x); a1 += ex * b2f(vuc.y);
        a2 += ex * b2f(vuc.z); a3 += ex * b2f(vuc.w);
        dsum += ex;
        payc = payn; kuc = kun; vuc = vun;
    }
    switch (cur_et) {
        case 0: Sv0[0]=a0; Sv0[1]=a1; Sv0[2]=a2; Sv0[3]=a3; break;
        case 1: Sv1[0]=a0; Sv1[1]=a1; Sv1[2]=a2; Sv1[3]=a3; break;
        case 2: Sv2[0]=a0; Sv2[1]=a1; Sv2[2]=a2; Sv2[3]=a3; break;
        case 3: Sv3[0]=a0; Sv3[1]=a1; Sv3[2]=a2; Sv3[3]=a3; break;
        case 4: Sv4[0]=a0; Sv4[1]=a1; Sv4[2]=a2; Sv4[3]=a3; break;
        default: break;
    }

    float inv = dsum > 0.f ? 1.f / dsum : 0.f;
    ushort4 o;
    o.x=f2b(Sv0[0]*inv); o.y=f2b(Sv0[1]*inv); o.z=f2b(Sv0[2]*inv); o.w=f2b(Sv0[3]*inv);
    *(ushort4*)(qwsv + rowb) = o;
    o.x=f2b(Sv1[0]*inv); o.y=f2b(Sv1[1]*inv); o.z=f2b(Sv1[2]*inv); o.w=f2b(Sv1[3]*inv);
    *(ushort4*)(qwsv + rowb + 256) = o;
    o.x=f2b(Sv2[0]*inv); o.y=f2b(Sv2[1]*inv); o.z=f2b(Sv2[2]*inv); o.w=f2b(Sv2[3]*inv);
    *(ushort4*)(qwsv + rowb + 512) = o;
    o.x=f2b(Sv3[0]*inv); o.y=f2b(Sv3[1]*inv); o.z=f2b(Sv3[2]*inv); o.w=f2b(Sv3[3]*inv);
    *(ushort4*)(qwsv + rowb + 768) = o;
    o.x=f2b(Sv4[0]*inv); o.y=f2b(Sv4[1]*inv); o.z=f2b(Sv4[2]*inv); o.w=f2b(Sv4[3]*inv);
    *(ushort4*)(qwsv + rowb + 1024) = o;
}

// ================= launch =================
extern "C" void kernel_launch(void* const* d_in, const int* in_sizes, int n_in,
                              void* d_out, int out_size, void* d_ws, size_t ws_size,
                              hipStream_t stream) {
    const float* x    = (const float*)d_in[0];
    const float* Wk   = (const float*)d_in[1];
    const float* Wq   = (const float*)d_in[2];
    const float* Wv   = (const float*)d_in[3];
    const float* Ratt = (const float*)d_in[4];
    const float* Rmsg = (const float*)d_in[5];
    const float* pri  = (const float*)d_in[6];
    const float* Wa   = (const float*)d_in[7];
    const float* skip = (const float*)d_in[8];
    const int* src   = (const int*)d_in[9];
    const int* dst   = (const int*)d_in[10];
    const int* etype = (const int*)d_in[11];
    const int* ntype = (const int*)d_in[12];

    int N = in_sizes[12];
    int E = in_sizes[9];
    const size_t NC = (size_t)N * CDIM;
    const int KEYS = N * ET;
    const int NB = (KEYS + 255) / 256;
    const int nblk = (N + 255) / 256;
    const size_t WTE = (size_t)NT * CDIM * CDIM;       // per weight tensor (u16 elems)
    const size_t QFE = (size_t)NT * QWC * CDIM;        // folded tensors (u16 elems)

    // ---- workspace (~190 MB) ----
    u16* kb   = (u16*)d_ws;                  // NC
    u16* vb   = kb + NC;                     // NC
    u16* qwsv = vb + NC;                     // 5*NC (qw then svn, in-place)
    u16* wtb  = qwsv + 5 * NC;               // 2*WTE (Wk, Wv transposed bf16)
    u16* qf_b = wtb + 2 * WTE;               // QFE
    u16* af_b = qf_b + QFE;                  // QFE
    int* rowptr = (int*)(af_b + QFE);        // KEYS+1  (persistent)
    int* perm   = rowptr + KEYS + 1;         // N       (persistent)
    int* epay   = perm + N;                  // E       (persistent)
    int* off    = epay + E;                  // NT+1    (persistent)
    // setup-only ints aliased into qwsv (dead before the projection GEMM writes it)
    int* khist = (int*)qwsv;                 // KEYS (zeroed)
    int* kscan = khist + KEYS;               // KEYS
    int* bsum  = kscan + KEYS;               // 1024
    int* bcnt  = bsum + 1024;                // NT*nblk
    int* base  = bcnt + NT * nblk;           // NT*nblk

    // xb (bf16 copy of x) lives in d_out scratch: NC u16 = half of out bytes;
    // fully dead before outgemm_k overwrites d_out.
    u16* xb = (u16*)d_out;

    hipMemsetAsync(khist, 0, (size_t)KEYS * sizeof(int), stream);

    // node buckets (atomic-free, stable)
    bhist_k<<<nblk, 256, 0, stream>>>(ntype, N, nblk, bcnt);
    bscan_k<<<1, 1024, 0, stream>>>(bcnt, base, off, NT * nblk, nblk, N);
    bscatter_k<<<nblk, 256, 0, stream>>>(ntype, N, nblk, base, perm);

    // edge counting sort by (dst, etype) -> CSR (epay packs et<<24 | src)
    ehist_k<<<(E + 255) / 256, 256, 0, stream>>>(dst, etype, E, khist);
    kscan1_k<<<NB, 256, 0, stream>>>(khist, kscan, bsum, KEYS);
    kscan2_k<<<1, 1024, 0, stream>>>(bsum, NB);
    kscan3r_k<<<NB, 256, 0, stream>>>(kscan, bsum, rowptr, KEYS, E);
    escatter_k<<<(E + 255) / 256, 256, 0, stream>>>(src, dst, etype, E, kscan, epay);

    // weight prep + x -> bf16
    wconv2_k<<<dim3(4, 4, 2 * NT), 256, 0, stream>>>(Wk, Wv, wtb);
    rfold_k<<<dim3(NT * ET * HD, 2), 256, 0, stream>>>(Wq, Ratt, qf_b, Wa, Rmsg, af_b);
    size_t n4 = NC / 4;
    f2bv_k<<<(int)((n4 + 255) / 256), 256, 0, stream>>>(x, xb, n4);

    int bpt = (N + 63) / 64;
    int npanel = NT * bpt;
    int ppad = (npanel + 7) & ~7;

    // fused k|v|qw projection, XCD-grouped, 64x128 tiles (14 per panel)
    gemmall_k<<<ppad * 14, 256, 0, stream>>>(xb, wtb, qf_b, kb, vb, qwsv,
                                             perm, off, N, bpt, npanel);

    // edge gather: merged loop, prefetch; svn (normalized) in-place over qw
    gather3_k<<<(N * 64 + 255) / 256, 256, 0, stream>>>(kb, vb, qwsv, pri, rowptr, epay, N);

    // out = svn @ (Rmsg*Wa), sigmoid-gated skip; 64x64 tiles, dbuf LDS, XCD-grouped
    outgemm_k<<<ppad * 4, 256, 0, stream>>>(qwsv, af_b, (float*)d_out, perm, off, N, bpt,
                                            npanel, x, skip);
}

// Round 23
// 384.884 us; speedup vs baseline: 1.0036x; 1.0036x over previous
//
#include <hip/hip_runtime.h>
#include <math.h>

#define CDIM 256
#define HD 8
#define DD 32
#define NT 3
#define ET 5
#define QWC (ET * CDIM)     // 1280

typedef unsigned short u16;
typedef __attribute__((ext_vector_type(8))) short s16x8;
typedef __attribute__((ext_vector_type(4))) float f32x4;

__device__ __forceinline__ float b2f(u16 u) { return __uint_as_float(((unsigned)u) << 16); }
__device__ __forceinline__ u16 f2b(float x) {
    unsigned u = __float_as_uint(x);
    return (u16)((u + 0x7FFF + ((u >> 16) & 1)) >> 16);
}

// ================= node-type buckets (atomic-free, stable) =================
__global__ void bhist_k(const int* __restrict__ ntype, int N, int nblk, int* __restrict__ bcnt) {
    __shared__ int wc[4][NT];
    int b = blockIdx.x, tid = threadIdx.x, lane = tid & 63, w = tid >> 6;
    int i = b * 256 + tid;
    int t = (i < N) ? ntype[i] : -1;
#pragma unroll
    for (int r = 0; r < NT; ++r) {
        unsigned long long m = __ballot(t == r);
        if (lane == 0) wc[w][r] = __popcll(m);
    }
    __syncthreads();
    if (tid < NT) bcnt[tid * nblk + b] = wc[0][tid] + wc[1][tid] + wc[2][tid] + wc[3][tid];
}

__global__ void bscan_k(const int* __restrict__ bcnt, int* __restrict__ base,
                        int* __restrict__ off, int total, int nblk, int N) {
    __shared__ int s[1024];
    int t = threadIdx.x;
    int v = (t < total) ? bcnt[t] : 0;
    s[t] = v; __syncthreads();
    for (int o = 1; o < 1024; o <<= 1) {
        int u = (t >= o) ? s[t - o] : 0; __syncthreads();
        s[t] += u; __syncthreads();
    }
    if (t < total) base[t] = s[t] - v;
    if (t < NT) off[t] = s[t * nblk] - bcnt[t * nblk];
    if (t == NT) off[NT] = N;
}

__global__ void bscatter_k(const int* __restrict__ ntype, int N, int nblk,
                           const int* __restrict__ base, int* __restrict__ perm) {
    __shared__ int wc[4][NT];
    __shared__ int woff[4][NT];
    int b = blockIdx.x, tid = threadIdx.x, lane = tid & 63, w = tid >> 6;
    int i = b * 256 + tid;
    int t = (i < N) ? ntype[i] : -1;
    unsigned long long mlt = (1ULL << lane) - 1;
    int rank = 0;
#pragma unroll
    for (int r = 0; r < NT; ++r) {
        unsigned long long m = __ballot(t == r);
        if (lane == 0) wc[w][r] = __popcll(m);
        if (t == r) rank = __popcll(m & mlt);
    }
    __syncthreads();
    if (tid == 0) {
#pragma unroll
        for (int r = 0; r < NT; ++r) {
            int a = 0;
#pragma unroll
            for (int w0 = 0; w0 < 4; ++w0) { woff[w0][r] = a; a += wc[w0][r]; }
        }
    }
    __syncthreads();
    if (t >= 0) perm[base[t * nblk + b] + woff[w][t] + rank] = i;
}

// ================= edge counting sort by key = dst*ET + etype =================
__global__ void ehist_k(const int* __restrict__ dst, const int* __restrict__ etype, int E,
                        int* __restrict__ khist) {
    int i = blockIdx.x * 256 + threadIdx.x;
    if (i < E) atomicAdd(&khist[dst[i] * ET + etype[i]], 1);
}

__global__ void kscan1_k(const int* __restrict__ khist, int* __restrict__ kscan,
                         int* __restrict__ bsum, int KEYS) {
    __shared__ int s[256];
    int b = blockIdx.x, t = threadIdx.x, i = b * 256 + t;
    int v = (i < KEYS) ? khist[i] : 0;
    s[t] = v; __syncthreads();
    for (int o = 1; o < 256; o <<= 1) {
        int u = (t >= o) ? s[t - o] : 0; __syncthreads();
        s[t] += u; __syncthreads();
    }
    if (i < KEYS) kscan[i] = s[t] - v;
    if (t == 255) bsum[b] = s[t];
}

__global__ void kscan2_k(int* __restrict__ bsum, int NB) {
    __shared__ int s[1024];
    int t = threadIdx.x;
    int v = (t < NB) ? bsum[t] : 0;
    s[t] = v; __syncthreads();
    for (int o = 1; o < 1024; o <<= 1) {
        int u = (t >= o) ? s[t - o] : 0; __syncthreads();
        s[t] += u; __syncthreads();
    }
    if (t < NB) bsum[t] = s[t] - v;
}

// merged: kscan += bsum, and rowptr = result (+ rowptr[KEYS] = E)
__global__ void kscan3r_k(int* __restrict__ kscan, const int* __restrict__ bsum,
                          int* __restrict__ rowptr, int KEYS, int E) {
    int i = blockIdx.x * 256 + threadIdx.x;
    if (i < KEYS) {
        int v = kscan[i] + bsum[blockIdx.x];
        kscan[i] = v;
        rowptr[i] = v;
    }
    if (i == 0) rowptr[KEYS] = E;
}

// epay packs (etype << 24) | src
__global__ void escatter_k(const int* __restrict__ src, const int* __restrict__ dst,
                           const int* __restrict__ etype, int E,
                           int* __restrict__ kscan, int* __restrict__ epay) {
    int e = blockIdx.x * 256 + threadIdx.x;
    if (e < E) {
        int et = etype[e];
        int pos = atomicAdd(&kscan[dst[e] * ET + et], 1);
        epay[pos] = (et << 24) | src[e];
    }
}

// ================= fp32 -> bf16 copy (x -> xb) =================
__global__ void f2bv_k(const float* __restrict__ in, u16* __restrict__ out, size_t n4) {
    size_t i = (size_t)blockIdx.x * 256 + threadIdx.x;
    if (i >= n4) return;
    float4 v = ((const float4*)in)[i];
    ushort4 o; o.x = f2b(v.x); o.y = f2b(v.y); o.z = f2b(v.z); o.w = f2b(v.w);
    ((ushort4*)out)[i] = o;
}

// ================= Wk|Wv [t][k][c] f32 -> Wtb[z][c][k] bf16 (z: 0..NT-1 = Wk, NT..2NT-1 = Wv)
__global__ __launch_bounds__(256) void wconv2_k(const float* __restrict__ Wk,
                                                const float* __restrict__ Wv,
                                                u16* __restrict__ Wtb) {
    __shared__ u16 s[64][72];
    int k0 = blockIdx.x * 64, c0 = blockIdx.y * 64, z = blockIdx.z;
    const float* Wp = (z < NT) ? (Wk + (size_t)z * CDIM * CDIM)
                               : (Wv + (size_t)(z - NT) * CDIM * CDIM);
    int r = threadIdx.x >> 2, q = (threadIdx.x & 3) * 16;
#pragma unroll
    for (int m = 0; m < 16; m += 4) {
        float4 v = *(const float4*)(Wp + (size_t)(k0 + r) * CDIM + c0 + q + m);
        s[r][q + m + 0] = f2b(v.x); s[r][q + m + 1] = f2b(v.y);
        s[r][q + m + 2] = f2b(v.z); s[r][q + m + 3] = f2b(v.w);
    }
    __syncthreads();
    int c = threadIdx.x >> 2, kq = (threadIdx.x & 3) * 16;
    u16* op = Wtb + ((size_t)z * CDIM + c0 + c) * CDIM + k0 + kq;
#pragma unroll
    for (int m = 0; m < 16; m += 4) {
        ushort4 o;
        o.x = s[kq + m + 0][c]; o.y = s[kq + m + 1][c];
        o.z = s[kq + m + 2][c]; o.w = s[kq + m + 3][c];
        *(ushort4*)(op + m) = o;
    }
}

// ===== merged folds. y=0: qf_b[t][et*256+h*32+m][c] = sum_f Wq[t][c][h32+f]*Ratt[et,h,m,f]
//                    y=1: af_b[t][col][et*256+h*32+f] = sum_m Rmsg[et,h,f,m]*Wa[t][h32+m][col]
__global__ __launch_bounds__(256) void rfold_k(const float* __restrict__ Wq,
                                               const float* __restrict__ Ratt,
                                               u16* __restrict__ qf_b,
                                               const float* __restrict__ Wa,
                                               const float* __restrict__ Rmsg,
                                               u16* __restrict__ af_b) {
    __shared__ float Rs[DD][DD];
    int b = blockIdx.x;
    int t = b / (ET * HD);
    int eh = b % (ET * HD);
    int et = eh >> 3, h = eh & 7;
    int tid = threadIdx.x;

    if (blockIdx.y == 0) {
        float4 rv = ((const float4*)(Ratt + (size_t)eh * (DD * DD)))[tid];
        int r = tid >> 3, c4 = (tid & 7) * 4;
        Rs[r][c4 + 0] = rv.x; Rs[r][c4 + 1] = rv.y;
        Rs[r][c4 + 2] = rv.z; Rs[r][c4 + 3] = rv.w;   // Rs[m][f]
        __syncthreads();

        int c = tid;
        const float* wr = Wq + (size_t)t * (CDIM * CDIM) + (size_t)c * CDIM + h * DD;
        float wrow[DD];
#pragma unroll
        for (int f = 0; f < DD; f += 4) {
            float4 v = *(const float4*)(wr + f);
            wrow[f] = v.x; wrow[f + 1] = v.y; wrow[f + 2] = v.z; wrow[f + 3] = v.w;
        }
        for (int m = 0; m < DD; ++m) {
            float acc = 0.f;
#pragma unroll
            for (int f = 0; f < DD; ++f) acc += wrow[f] * Rs[m][f];
            qf_b[((size_t)t * QWC + et * 256 + h * 32 + m) * CDIM + c] = f2b(acc);
        }
    } else {
        float4 rv = ((const float4*)(Rmsg + (size_t)eh * (DD * DD)))[tid];
        int r = tid >> 3, c4 = (tid & 7) * 4;
        Rs[r][c4 + 0] = rv.x; Rs[r][c4 + 1] = rv.y;
        Rs[r][c4 + 2] = rv.z; Rs[r][c4 + 3] = rv.w;   // Rs[f][m]
        __syncthreads();

        int col = tid;
        float wcol[DD];
#pragma unroll
        for (int m = 0; m < DD; ++m)
            wcol[m] = Wa[(size_t)t * (CDIM * CDIM) + (size_t)(h * 32 + m) * CDIM + col];

        u16* op = af_b + ((size_t)t * CDIM + col) * QWC + et * 256 + h * 32;
        for (int f = 0; f < DD; ++f) {
            float acc = 0.f;
#pragma unroll
            for (int m = 0; m < DD; ++m) acc += Rs[f][m] * wcol[m];
            op[f] = f2b(acc);
        }
    }
}

// ================= fused projection GEMM: [k|v|qw] = xb @ {Wk,Wv,Wq*Ratt} =================
// XCD-grouped 1D grid; 64x128 block tile; BK=32, [..][40] LDS layout.
__global__ __launch_bounds__(256) void gemmall_k(
    const u16* __restrict__ xb, const u16* __restrict__ wtb, const u16* __restrict__ qf_b,
    u16* __restrict__ kb, u16* __restrict__ vb, u16* __restrict__ qwsv,
    const int* __restrict__ perm, const int* __restrict__ off, int N, int bpt, int npanel)
{
    __shared__ u16 As[64][40];
    __shared__ u16 Bs[128][40];
    __shared__ int ridx[64];

    int bid = blockIdx.x;
    int xcd = bid & 7;
    int rr_ = bid >> 3;
    int g = rr_ / 14, bx = rr_ % 14;
    int p = g * 8 + xcd;
    if (p >= npanel) return;
    int t = p / bpt, bi = p % bpt;

    int i0 = off[t] + bi * 64, iend = off[t + 1];
    if (i0 >= iend) return;
    int tid = threadIdx.x;

    u16* out; int ostr, oc0; const u16* bslab;
    const size_t CC = (size_t)CDIM * CDIM;
    if (bx < 2)      { out = kb;   ostr = CDIM; oc0 = bx * 128;       bslab = wtb + (size_t)t * CC; }
    else if (bx < 4) { out = vb;   ostr = CDIM; oc0 = (bx - 2) * 128; bslab = wtb + (size_t)(NT + t) * CC; }
    else             { out = qwsv; ostr = QWC;  oc0 = (bx - 4) * 128; bslab = qf_b + (size_t)t * QWC * CDIM; }

    if (tid < 64) ridx[tid] = (i0 + tid < iend) ? perm[i0 + tid] : -1;
    __syncthreads();

    int sr = tid >> 2, sq = (tid & 3) * 8;     // A staging: 4 thr/row, 16B each
    int srB = tid >> 1, sqB = (tid & 1) * 16;  // B staging: 2 thr/row, 32B each
    int ar = ridx[sr];
    const u16* asrc = xb + (size_t)(ar < 0 ? 0 : ar) * CDIM + sq;
    const u16* bsrc = bslab + (size_t)(oc0 + srB) * CDIM + sqB;

    int lane = tid & 63, wid = tid >> 6;
    int wr = wid >> 1, wc = wid & 1;
    int l15 = lane & 15, lk = (lane >> 4) * 8;

    f32x4 acc[2][4];
#pragma unroll
    for (int mi = 0; mi < 2; ++mi)
#pragma unroll
        for (int j = 0; j < 4; ++j)
            acc[mi][j] = (f32x4){0.f, 0.f, 0.f, 0.f};

    uint4 apre = make_uint4(0, 0, 0, 0);
    if (ar >= 0) apre = *(const uint4*)(asrc);
    uint4 bp0 = *(const uint4*)(bsrc);
    uint4 bp1 = *(const uint4*)(bsrc + 8);

    for (int k0 = 0; k0 < CDIM; k0 += 32) {
        __syncthreads();
        *(uint4*)&As[sr][sq] = apre;
        *(uint4*)&Bs[srB][sqB] = bp0;
        *(uint4*)&Bs[srB][sqB + 8] = bp1;
        __syncthreads();

        if (k0 + 32 < CDIM) {
            if (ar >= 0) apre = *(const uint4*)(asrc + k0 + 32);
            bp0 = *(const uint4*)(bsrc + k0 + 32);
            bp1 = *(const uint4*)(bsrc + k0 + 40);
        }

        s16x8 af0 = *(const s16x8*)&As[wr * 32 + l15][lk];
        s16x8 af1 = *(const s16x8*)&As[wr * 32 + 16 + l15][lk];
#pragma unroll
        for (int j = 0; j < 4; ++j) {
            s16x8 bf = *(const s16x8*)&Bs[wc * 64 + j * 16 + l15][lk];
            acc[0][j] = __builtin_amdgcn_mfma_f32_16x16x32_bf16(af0, bf, acc[0][j], 0, 0, 0);
            acc[1][j] = __builtin_amdgcn_mfma_f32_16x16x32_bf16(af1, bf, acc[1][j], 0, 0, 0);
        }
    }

    int rbase = wr * 32 + (lane >> 4) * 4;
#pragma unroll
    for (int mi = 0; mi < 2; ++mi) {
#pragma unroll
        for (int r = 0; r < 4; ++r) {
            int node = ridx[rbase + mi * 16 + r];
            if (node < 0) continue;
            size_t b0 = (size_t)node * ostr + oc0 + wc * 64 + l15;
#pragma unroll
            for (int j = 0; j < 4; ++j)
                out[b0 + j * 16] = f2b(acc[mi][j][r]);
        }
    }
}

// ================= out GEMM v6: out = svn @ af_b (K=1280), 64x64 tiles, dbuf LDS ======
// 4 col-tiles per row-panel, XCD-grouped. Double-buffered A staging: ONE barrier per
// 64-k chunk (issue loads -> barrier -> compute As[cur] -> write As[cur^1]).
// B fragments direct from L2-resident af_b.
__global__ __launch_bounds__(256) void outgemm_k(
    const u16* __restrict__ svn, const u16* __restrict__ af_b, float* __restrict__ out,
    const int* __restrict__ perm, const int* __restrict__ off, int N, int bpt, int npanel,
    const float* __restrict__ x, const float* __restrict__ skip)
{
    __shared__ u16 As[2][64][68];
    __shared__ int ridx[64];

    int bid = blockIdx.x;
    int xcd = bid & 7;
    int rr_ = bid >> 3;
    int g = rr_ / 4, cx = rr_ % 4;
    int p = g * 8 + xcd;
    if (p >= npanel) return;
    int t = p / bpt, bi = p % bpt;
    int i0 = off[t] + bi * 64, iend = off[t + 1];
    if (i0 >= iend) return;
    int tid = threadIdx.x;
    if (tid < 64) ridx[tid] = (i0 + tid < iend) ? perm[i0 + tid] : -1;
    __syncthreads();

    int lane = tid & 63, y = tid >> 6;     // wave y owns out cols cx*64 + y*16 .. +16
    int l15 = lane & 15, lq = lane >> 4;
    int lk = lq * 8;
    int colb = cx * 64 + y * 16;

    int sr = tid >> 2, sc = (tid & 3) * 16;
    int ar = ridx[sr];
    const u16* asrc = svn + (size_t)(ar < 0 ? 0 : ar) * QWC + sc;
    const u16* brow = af_b + ((size_t)t * CDIM + colb + l15) * QWC;

    f32x4 acc[4];
#pragma unroll
    for (int mi = 0; mi < 4; ++mi) acc[mi] = (f32x4){0.f, 0.f, 0.f, 0.f};

    uint4 a0 = make_uint4(0, 0, 0, 0), a1 = make_uint4(0, 0, 0, 0);
    if (ar >= 0) {
        a0 = *(const uint4*)(asrc);
        a1 = *(const uint4*)(asrc + 8);
    }
    *(uint4*)&As[0][sr][sc] = a0;
    *(uint4*)&As[0][sr][sc + 8] = a1;

    s16x8 bf0 = *(const s16x8*)(brow + lk);
    s16x8 bf1 = *(const s16x8*)(brow + 32 + lk);

    for (int kc = 0; kc < 20; ++kc) {
        int cur = kc & 1;
        s16x8 b0c = bf0, b1c = bf1;
        if (kc + 1 < 20) {
            int ko = (kc + 1) * 64;
            if (ar >= 0) {
                a0 = *(const uint4*)(asrc + ko);
                a1 = *(const uint4*)(asrc + ko + 8);
            }
            bf0 = *(const s16x8*)(brow + ko + lk);
            bf1 = *(const s16x8*)(brow + ko + 32 + lk);
        }
        __syncthreads();   // all waves' As[cur] writes (prev iter) complete; prev reads of As[cur^1] done

#pragma unroll
        for (int mi = 0; mi < 4; ++mi) {
            s16x8 af0 = *(const s16x8*)&As[cur][mi * 16 + l15][lk];
            s16x8 af1 = *(const s16x8*)&As[cur][mi * 16 + l15][32 + lk];
            acc[mi] = __builtin_amdgcn_mfma_f32_16x16x32_bf16(af0, b0c, acc[mi], 0, 0, 0);
            acc[mi] = __builtin_amdgcn_mfma_f32_16x16x32_bf16(af1, b1c, acc[mi], 0, 0, 0);
        }

        if (kc + 1 < 20) {
            *(uint4*)&As[cur ^ 1][sr][sc] = a0;
            *(uint4*)&As[cur ^ 1][sr][sc + 8] = a1;
        }
    }

    float alpha = 1.f / (1.f + __expf(-skip[t]));
    float beta = 1.f - alpha;
#pragma unroll
    for (int mi = 0; mi < 4; ++mi) {
#pragma unroll
        for (int r = 0; r < 4; ++r) {
            int node = ridx[mi * 16 + lq * 4 + r];
            if (node < 0) continue;
            size_t b0 = (size_t)node * CDIM + colb + l15;
            out[b0] = acc[mi][r] * alpha + x[b0] * beta;
        }
    }
}

// ================= gather v3: one wave per dst; single merged edge loop (sorted by et),
// 2-deep prefetch, uniform-branch segment transitions, svn in-place over qw ============
__global__ __launch_bounds__(256) void gather3_k(
    const u16* __restrict__ kb, const u16* __restrict__ vb, u16* __restrict__ qwsv,
    const float* __restrict__ pri, const int* __restrict__ rowptr, const int* __restrict__ epay,
    int N)
{
    int d = (blockIdx.x * 256 + threadIdx.x) >> 6;
    if (d >= N) return;
    int lane = threadIdx.x & 63, h = lane >> 3;
    const float rsD = 0.17677669529663687f;
    size_t rowb = (size_t)d * QWC + lane * 4;

    ushort4 qu0 = *(const ushort4*)(qwsv + rowb);
    ushort4 qu1 = *(const ushort4*)(qwsv + rowb + 256);
    ushort4 qu2 = *(const ushort4*)(qwsv + rowb + 512);
    ushort4 qu3 = *(const ushort4*)(qwsv + rowb + 768);
    ushort4 qu4 = *(const ushort4*)(qwsv + rowb + 1024);

    int p0 = __builtin_amdgcn_readfirstlane(rowptr[d * ET]);
    int p1 = __builtin_amdgcn_readfirstlane(rowptr[d * ET + ET]);

    float Sv0[4] = {0,0,0,0}, Sv1[4] = {0,0,0,0}, Sv2[4] = {0,0,0,0};
    float Sv3[4] = {0,0,0,0}, Sv4[4] = {0,0,0,0};
    float a0 = 0.f, a1 = 0.f, a2 = 0.f, a3 = 0.f, dsum = 0.f;
    int cur_et = -1;
    float cq0 = 0.f, cq1 = 0.f, cq2 = 0.f, cq3 = 0.f, cpf = 0.f;

    int payc = 0; ushort4 kuc = {0,0,0,0}, vuc = {0,0,0,0};
    if (p0 < p1) {
        payc = epay[p0];
        int s = payc & 0xFFFFFF;
        kuc = *(const ushort4*)(kb + (size_t)s * CDIM + lane * 4);
        vuc = *(const ushort4*)(vb + (size_t)s * CDIM + lane * 4);
    }

    for (int p = p0; p < p1; ++p) {
        int payn = 0; ushort4 kun = {0,0,0,0}, vun = {0,0,0,0};
        if (p + 1 < p1) {
            payn = epay[p + 1];
            int sn = payn & 0xFFFFFF;
            kun = *(const ushort4*)(kb + (size_t)sn * CDIM + lane * 4);
            vun = *(const ushort4*)(vb + (size_t)sn * CDIM + lane * 4);
        }
        int et = __builtin_amdgcn_readfirstlane(payc) >> 24;
        if (et != cur_et) {
            switch (cur_et) {
                case 0: Sv0[0]=a0; Sv0[1]=a1; Sv0[2]=a2; Sv0[3]=a3; break;
                case 1: Sv1[0]=a0; Sv1[1]=a1; Sv1[2]=a2; Sv1[3]=a3; break;
                case 2: Sv2[0]=a0; Sv2[1]=a1; Sv2[2]=a2; Sv2[3]=a3; break;
                case 3: Sv3[0]=a0; Sv3[1]=a1; Sv3[2]=a2; Sv3[3]=a3; break;
                default: break;
            }
            a0 = a1 = a2 = a3 = 0.f;
            cur_et = et;
            ushort4 q = (et == 0) ? qu0 : (et == 1) ? qu1 : (et == 2) ? qu2
                       : (et == 3) ? qu3 : qu4;
            cq0 = b2f(q.x); cq1 = b2f(q.y); cq2 = b2f(q.z); cq3 = b2f(q.w);
            cpf = pri[et * HD + h] * rsD;
        }
        float t = b2f(kuc.x) * cq0 + b2f(kuc.y) * cq1 + b2f(kuc.z) * cq2 + b2f(kuc.w) * cq3;
        t += __shfl_xor(t, 1, 8);
        t += __shfl_xor(t, 2, 8);
        t += __shfl_xor(t, 4, 8);
        float ex = __expf(t * cpf);
        a0 += ex * b2f(vuc.x); a1 += ex * b2f(vuc.y);
        a2 += ex * b2f(vuc.z); a3 += ex * b2f(vuc.w);
        dsum += ex;
        payc = payn; kuc = kun; vuc = vun;
    }
    switch (cur_et) {
        case 0: Sv0[0]=a0; Sv0[1]=a1; Sv0[2]=a2; Sv0[3]=a3; break;
        case 1: Sv1[0]=a0; Sv1[1]=a1; Sv1[2]=a2; Sv1[3]=a3; break;
        case 2: Sv2[0]=a0; Sv2[1]=a1; Sv2[2]=a2; Sv2[3]=a3; break;
        case 3: Sv3[0]=a0; Sv3[1]=a1; Sv3[2]=a2; Sv3[3]=a3; break;
        case 4: Sv4[0]=a0; Sv4[1]=a1; Sv4[2]=a2; Sv4[3]=a3; break;
        default: break;
    }

    float inv = dsum > 0.f ? 1.f / dsum : 0.f;
    ushort4 o;
    o.x=f2b(Sv0[0]*inv); o.y=f2b(Sv0[1]*inv); o.z=f2b(Sv0[2]*inv); o.w=f2b(Sv0[3]*inv);
    *(ushort4*)(qwsv + rowb) = o;
    o.x=f2b(Sv1[0]*inv); o.y=f2b(Sv1[1]*inv); o.z=f2b(Sv1[2]*inv); o.w=f2b(Sv1[3]*inv);
    *(ushort4*)(qwsv + rowb + 256) = o;
    o.x=f2b(Sv2[0]*inv); o.y=f2b(Sv2[1]*inv); o.z=f2b(Sv2[2]*inv); o.w=f2b(Sv2[3]*inv);
    *(ushort4*)(qwsv + rowb + 512) = o;
    o.x=f2b(Sv3[0]*inv); o.y=f2b(Sv3[1]*inv); o.z=f2b(Sv3[2]*inv); o.w=f2b(Sv3[3]*inv);
    *(ushort4*)(qwsv + rowb + 768) = o;
    o.x=f2b(Sv4[0]*inv); o.y=f2b(Sv4[1]*inv); o.z=f2b(Sv4[2]*inv); o.w=f2b(Sv4[3]*inv);
    *(ushort4*)(qwsv + rowb + 1024) = o;
}

// ================= launch =================
extern "C" void kernel_launch(void* const* d_in, const int* in_sizes, int n_in,
                              void* d_out, int out_size, void* d_ws, size_t ws_size,
                              hipStream_t stream) {
    const float* x    = (const float*)d_in[0];
    const float* Wk   = (const float*)d_in[1];
    const float* Wq   = (const float*)d_in[2];
    const float* Wv   = (const float*)d_in[3];
    const float* Ratt = (const float*)d_in[4];
    const float* Rmsg = (const float*)d_in[5];
    const float* pri  = (const float*)d_in[6];
    const float* Wa   = (const float*)d_in[7];
    const float* skip = (const float*)d_in[8];
    const int* src   = (const int*)d_in[9];
    const int* dst   = (const int*)d_in[10];
    const int* etype = (const int*)d_in[11];
    const int* ntype = (const int*)d_in[12];

    int N = in_sizes[12];
    int E = in_sizes[9];
    const size_t NC = (size_t)N * CDIM;
    const int KEYS = N * ET;
    const int NB = (KEYS + 255) / 256;
    const int nblk = (N + 255) / 256;
    const size_t WTE = (size_t)NT * CDIM * CDIM;       // per weight tensor (u16 elems)
    const size_t QFE = (size_t)NT * QWC * CDIM;        // folded tensors (u16 elems)

    // ---- workspace (~190 MB) ----
    u16* kb   = (u16*)d_ws;                  // NC
    u16* vb   = kb + NC;                     // NC
    u16* qwsv = vb + NC;                     // 5*NC (qw then svn, in-place)
    u16* wtb  = qwsv + 5 * NC;               // 2*WTE (Wk, Wv transposed bf16)
    u16* qf_b = wtb + 2 * WTE;               // QFE
    u16* af_b = qf_b + QFE;                  // QFE
    int* rowptr = (int*)(af_b + QFE);        // KEYS+1  (persistent)
    int* perm   = rowptr + KEYS + 1;         // N       (persistent)
    int* epay   = perm + N;                  // E       (persistent)
    int* off    = epay + E;                  // NT+1    (persistent)
    // setup-only ints aliased into qwsv (dead before the projection GEMM writes it)
    int* khist = (int*)qwsv;                 // KEYS (zeroed)
    int* kscan = khist + KEYS;               // KEYS
    int* bsum  = kscan + KEYS;               // 1024
    int* bcnt  = bsum + 1024;                // NT*nblk
    int* base  = bcnt + NT * nblk;           // NT*nblk

    // xb (bf16 copy of x) lives in d_out scratch: NC u16 = half of out bytes;
    // fully dead before outgemm_k overwrites d_out.
    u16* xb = (u16*)d_out;

    hipMemsetAsync(khist, 0, (size_t)KEYS * sizeof(int), stream);

    // node buckets (atomic-free, stable)
    bhist_k<<<nblk, 256, 0, stream>>>(ntype, N, nblk, bcnt);
    bscan_k<<<1, 1024, 0, stream>>>(bcnt, base, off, NT * nblk, nblk, N);
    bscatter_k<<<nblk, 256, 0, stream>>>(ntype, N, nblk, base, perm);

    // edge counting sort by (dst, etype) -> CSR (epay packs et<<24 | src)
    ehist_k<<<(E + 255) / 256, 256, 0, stream>>>(dst, etype, E, khist);
    kscan1_k<<<NB, 256, 0, stream>>>(khist, kscan, bsum, KEYS);
    kscan2_k<<<1, 1024, 0, stream>>>(bsum, NB);
    kscan3r_k<<<NB, 256, 0, stream>>>(kscan, bsum, rowptr, KEYS, E);
    escatter_k<<<(E + 255) / 256, 256, 0, stream>>>(src, dst, etype, E, kscan, epay);

    // weight prep + x -> bf16
    wconv2_k<<<dim3(4, 4, 2 * NT), 256, 0, stream>>>(Wk, Wv, wtb);
    rfold_k<<<dim3(NT * ET * HD, 2), 256, 0, stream>>>(Wq, Ratt, qf_b, Wa, Rmsg, af_b);
    size_t n4 = NC / 4;
    f2bv_k<<<(int)((n4 + 255) / 256), 256, 0, stream>>>(x, xb, n4);

    int bpt = (N + 63) / 64;
    int npanel = NT * bpt;
    int ppad = (npanel + 7) & ~7;

    // fused k|v|qw projection, XCD-grouped, 64x128 tiles (14 per panel)
    gemmall_k<<<ppad * 14, 256, 0, stream>>>(xb, wtb, qf_b, kb, vb, qwsv,
                                             perm, off, N, bpt, npanel);

    // edge gather: merged loop, prefetch; svn (normalized) in-place over qw
    gather3_k<<<(N * 64 + 255) / 256, 256, 0, stream>>>(kb, vb, qwsv, pri, rowptr, epay, N);

    // out = svn @ (Rmsg*Wa), sigmoid-gated skip; 64x64 tiles, dbuf LDS, XCD-grouped
    outgemm_k<<<ppad * 4, 256, 0, stream>>>(qwsv, af_b, (float*)d_out, perm, off, N, bpt,
                                            npanel, x, skip);
}

// Round 24
// 375.189 us; speedup vs baseline: 1.0295x; 1.0258x over previous
//
#include <hip/hip_runtime.h>
#include <math.h>

#define CDIM 256
#define HD 8
#define DD 32
#define NT 3
#define ET 5
#define QWC (ET * CDIM)     // 1280

typedef unsigned short u16;
typedef __attribute__((ext_vector_type(8))) short s16x8;
typedef __attribute__((ext_vector_type(4))) float f32x4;

__device__ __forceinline__ float b2f(u16 u) { return __uint_as_float(((unsigned)u) << 16); }
__device__ __forceinline__ u16 f2b(float x) {
    unsigned u = __float_as_uint(x);
    return (u16)((u + 0x7FFF + ((u >> 16) & 1)) >> 16);
}

// ================= node-type buckets (atomic-free, stable) =================
__global__ void bhist_k(const int* __restrict__ ntype, int N, int nblk, int* __restrict__ bcnt) {
    __shared__ int wc[4][NT];
    int b = blockIdx.x, tid = threadIdx.x, lane = tid & 63, w = tid >> 6;
    int i = b * 256 + tid;
    int t = (i < N) ? ntype[i] : -1;
#pragma unroll
    for (int r = 0; r < NT; ++r) {
        unsigned long long m = __ballot(t == r);
        if (lane == 0) wc[w][r] = __popcll(m);
    }
    __syncthreads();
    if (tid < NT) bcnt[tid * nblk + b] = wc[0][tid] + wc[1][tid] + wc[2][tid] + wc[3][tid];
}

__global__ void bscan_k(const int* __restrict__ bcnt, int* __restrict__ base,
                        int* __restrict__ off, int total, int nblk, int N) {
    __shared__ int s[1024];
    int t = threadIdx.x;
    int v = (t < total) ? bcnt[t] : 0;
    s[t] = v; __syncthreads();
    for (int o = 1; o < 1024; o <<= 1) {
        int u = (t >= o) ? s[t - o] : 0; __syncthreads();
        s[t] += u; __syncthreads();
    }
    if (t < total) base[t] = s[t] - v;
    if (t < NT) off[t] = s[t * nblk] - bcnt[t * nblk];
    if (t == NT) off[NT] = N;
}

__global__ void bscatter_k(const int* __restrict__ ntype, int N, int nblk,
                           const int* __restrict__ base, int* __restrict__ perm) {
    __shared__ int wc[4][NT];
    __shared__ int woff[4][NT];
    int b = blockIdx.x, tid = threadIdx.x, lane = tid & 63, w = tid >> 6;
    int i = b * 256 + tid;
    int t = (i < N) ? ntype[i] : -1;
    unsigned long long mlt = (1ULL << lane) - 1;
    int rank = 0;
#pragma unroll
    for (int r = 0; r < NT; ++r) {
        unsigned long long m = __ballot(t == r);
        if (lane == 0) wc[w][r] = __popcll(m);
        if (t == r) rank = __popcll(m & mlt);
    }
    __syncthreads();
    if (tid == 0) {
#pragma unroll
        for (int r = 0; r < NT; ++r) {
            int a = 0;
#pragma unroll
            for (int w0 = 0; w0 < 4; ++w0) { woff[w0][r] = a; a += wc[w0][r]; }
        }
    }
    __syncthreads();
    if (t >= 0) perm[base[t * nblk + b] + woff[w][t] + rank] = i;
}

// ================= edge counting sort by key = dst*ET + etype =================
__global__ void ehist_k(const int* __restrict__ dst, const int* __restrict__ etype, int E,
                        int* __restrict__ khist) {
    int i = blockIdx.x * 256 + threadIdx.x;
    if (i < E) atomicAdd(&khist[dst[i] * ET + etype[i]], 1);
}

__global__ void kscan1_k(const int* __restrict__ khist, int* __restrict__ kscan,
                         int* __restrict__ bsum, int KEYS) {
    __shared__ int s[256];
    int b = blockIdx.x, t = threadIdx.x, i = b * 256 + t;
    int v = (i < KEYS) ? khist[i] : 0;
    s[t] = v; __syncthreads();
    for (int o = 1; o < 256; o <<= 1) {
        int u = (t >= o) ? s[t - o] : 0; __syncthreads();
        s[t] += u; __syncthreads();
    }
    if (i < KEYS) kscan[i] = s[t] - v;
    if (t == 255) bsum[b] = s[t];
}

__global__ void kscan2_k(int* __restrict__ bsum, int NB) {
    __shared__ int s[1024];
    int t = threadIdx.x;
    int v = (t < NB) ? bsum[t] : 0;
    s[t] = v; __syncthreads();
    for (int o = 1; o < 1024; o <<= 1) {
        int u = (t >= o) ? s[t - o] : 0; __syncthreads();
        s[t] += u; __syncthreads();
    }
    if (t < NB) bsum[t] = s[t] - v;
}

// merged: kscan += bsum, and rowptr = result (+ rowptr[KEYS] = E)
__global__ void kscan3r_k(int* __restrict__ kscan, const int* __restrict__ bsum,
                          int* __restrict__ rowptr, int KEYS, int E) {
    int i = blockIdx.x * 256 + threadIdx.x;
    if (i < KEYS) {
        int v = kscan[i] + bsum[blockIdx.x];
        kscan[i] = v;
        rowptr[i] = v;
    }
    if (i == 0) rowptr[KEYS] = E;
}

// epay packs (etype << 24) | src
__global__ void escatter_k(const int* __restrict__ src, const int* __restrict__ dst,
                           const int* __restrict__ etype, int E,
                           int* __restrict__ kscan, int* __restrict__ epay) {
    int e = blockIdx.x * 256 + threadIdx.x;
    if (e < E) {
        int et = etype[e];
        int pos = atomicAdd(&kscan[dst[e] * ET + et], 1);
        epay[pos] = (et << 24) | src[e];
    }
}

// ================= fp32 -> bf16 copy (x -> xb) =================
__global__ void f2bv_k(const float* __restrict__ in, u16* __restrict__ out, size_t n4) {
    size_t i = (size_t)blockIdx.x * 256 + threadIdx.x;
    if (i >= n4) return;
    float4 v = ((const float4*)in)[i];
    ushort4 o; o.x = f2b(v.x); o.y = f2b(v.y); o.z = f2b(v.z); o.w = f2b(v.w);
    ((ushort4*)out)[i] = o;
}

// ================= Wk|Wv [t][k][c] f32 -> Wtb[z][c][k] bf16 (z: 0..NT-1 = Wk, NT..2NT-1 = Wv)
__global__ __launch_bounds__(256) void wconv2_k(const float* __restrict__ Wk,
                                                const float* __restrict__ Wv,
                                                u16* __restrict__ Wtb) {
    __shared__ u16 s[64][72];
    int k0 = blockIdx.x * 64, c0 = blockIdx.y * 64, z = blockIdx.z;
    const float* Wp = (z < NT) ? (Wk + (size_t)z * CDIM * CDIM)
                               : (Wv + (size_t)(z - NT) * CDIM * CDIM);
    int r = threadIdx.x >> 2, q = (threadIdx.x & 3) * 16;
#pragma unroll
    for (int m = 0; m < 16; m += 4) {
        float4 v = *(const float4*)(Wp + (size_t)(k0 + r) * CDIM + c0 + q + m);
        s[r][q + m + 0] = f2b(v.x); s[r][q + m + 1] = f2b(v.y);
        s[r][q + m + 2] = f2b(v.z); s[r][q + m + 3] = f2b(v.w);
    }
    __syncthreads();
    int c = threadIdx.x >> 2, kq = (threadIdx.x & 3) * 16;
    u16* op = Wtb + ((size_t)z * CDIM + c0 + c) * CDIM + k0 + kq;
#pragma unroll
    for (int m = 0; m < 16; m += 4) {
        ushort4 o;
        o.x = s[kq + m + 0][c]; o.y = s[kq + m + 1][c];
        o.z = s[kq + m + 2][c]; o.w = s[kq + m + 3][c];
        *(ushort4*)(op + m) = o;
    }
}

// ===== merged folds. y=0: qf_b[t][et*256+h*32+m][c] = sum_f Wq[t][c][h32+f]*Ratt[et,h,m,f]
//                    y=1: af_b[t][col][et*256+h*32+f] = sum_m Rmsg[et,h,f,m]*Wa[t][h32+m][col]
__global__ __launch_bounds__(256) void rfold_k(const float* __restrict__ Wq,
                                               const float* __restrict__ Ratt,
                                               u16* __restrict__ qf_b,
                                               const float* __restrict__ Wa,
                                               const float* __restrict__ Rmsg,
                                               u16* __restrict__ af_b) {
    __shared__ float Rs[DD][DD];
    int b = blockIdx.x;
    int t = b / (ET * HD);
    int eh = b % (ET * HD);
    int et = eh >> 3, h = eh & 7;
    int tid = threadIdx.x;

    if (blockIdx.y == 0) {
        float4 rv = ((const float4*)(Ratt + (size_t)eh * (DD * DD)))[tid];
        int r = tid >> 3, c4 = (tid & 7) * 4;
        Rs[r][c4 + 0] = rv.x; Rs[r][c4 + 1] = rv.y;
        Rs[r][c4 + 2] = rv.z; Rs[r][c4 + 3] = rv.w;   // Rs[m][f]
        __syncthreads();

        int c = tid;
        const float* wr = Wq + (size_t)t * (CDIM * CDIM) + (size_t)c * CDIM + h * DD;
        float wrow[DD];
#pragma unroll
        for (int f = 0; f < DD; f += 4) {
            float4 v = *(const float4*)(wr + f);
            wrow[f] = v.x; wrow[f + 1] = v.y; wrow[f + 2] = v.z; wrow[f + 3] = v.w;
        }
        for (int m = 0; m < DD; ++m) {
            float acc = 0.f;
#pragma unroll
            for (int f = 0; f < DD; ++f) acc += wrow[f] * Rs[m][f];
            qf_b[((size_t)t * QWC + et * 256 + h * 32 + m) * CDIM + c] = f2b(acc);
        }
    } else {
        float4 rv = ((const float4*)(Rmsg + (size_t)eh * (DD * DD)))[tid];
        int r = tid >> 3, c4 = (tid & 7) * 4;
        Rs[r][c4 + 0] = rv.x; Rs[r][c4 + 1] = rv.y;
        Rs[r][c4 + 2] = rv.z; Rs[r][c4 + 3] = rv.w;   // Rs[f][m]
        __syncthreads();

        int col = tid;
        float wcol[DD];
#pragma unroll
        for (int m = 0; m < DD; ++m)
            wcol[m] = Wa[(size_t)t * (CDIM * CDIM) + (size_t)(h * 32 + m) * CDIM + col];

        u16* op = af_b + ((size_t)t * CDIM + col) * QWC + et * 256 + h * 32;
        for (int f = 0; f < DD; ++f) {
            float acc = 0.f;
#pragma unroll
            for (int m = 0; m < DD; ++m) acc += Rs[f][m] * wcol[m];
            op[f] = f2b(acc);
        }
    }
}

// ================= fused projection GEMM: [k|v|qw] = xb @ {Wk,Wv,Wq*Ratt} =================
// XCD-grouped 1D grid; 64x128 block tile; BK=32, [..][40] LDS layout.
__global__ __launch_bounds__(256) void gemmall_k(
    const u16* __restrict__ xb, const u16* __restrict__ wtb, const u16* __restrict__ qf_b,
    u16* __restrict__ kb, u16* __restrict__ vb, u16* __restrict__ qwsv,
    const int* __restrict__ perm, const int* __restrict__ off, int N, int bpt, int npanel)
{
    __shared__ u16 As[64][40];
    __shared__ u16 Bs[128][40];
    __shared__ int ridx[64];

    int bid = blockIdx.x;
    int xcd = bid & 7;
    int rr_ = bid >> 3;
    int g = rr_ / 14, bx = rr_ % 14;
    int p = g * 8 + xcd;
    if (p >= npanel) return;
    int t = p / bpt, bi = p % bpt;

    int i0 = off[t] + bi * 64, iend = off[t + 1];
    if (i0 >= iend) return;
    int tid = threadIdx.x;

    u16* out; int ostr, oc0; const u16* bslab;
    const size_t CC = (size_t)CDIM * CDIM;
    if (bx < 2)      { out = kb;   ostr = CDIM; oc0 = bx * 128;       bslab = wtb + (size_t)t * CC; }
    else if (bx < 4) { out = vb;   ostr = CDIM; oc0 = (bx - 2) * 128; bslab = wtb + (size_t)(NT + t) * CC; }
    else             { out = qwsv; ostr = QWC;  oc0 = (bx - 4) * 128; bslab = qf_b + (size_t)t * QWC * CDIM; }

    if (tid < 64) ridx[tid] = (i0 + tid < iend) ? perm[i0 + tid] : -1;
    __syncthreads();

    int sr = tid >> 2, sq = (tid & 3) * 8;     // A staging: 4 thr/row, 16B each
    int srB = tid >> 1, sqB = (tid & 1) * 16;  // B staging: 2 thr/row, 32B each
    int ar = ridx[sr];
    const u16* asrc = xb + (size_t)(ar < 0 ? 0 : ar) * CDIM + sq;
    const u16* bsrc = bslab + (size_t)(oc0 + srB) * CDIM + sqB;

    int lane = tid & 63, wid = tid >> 6;
    int wr = wid >> 1, wc = wid & 1;
    int l15 = lane & 15, lk = (lane >> 4) * 8;

    f32x4 acc[2][4];
#pragma unroll
    for (int mi = 0; mi < 2; ++mi)
#pragma unroll
        for (int j = 0; j < 4; ++j)
            acc[mi][j] = (f32x4){0.f, 0.f, 0.f, 0.f};

    uint4 apre = make_uint4(0, 0, 0, 0);
    if (ar >= 0) apre = *(const uint4*)(asrc);
    uint4 bp0 = *(const uint4*)(bsrc);
    uint4 bp1 = *(const uint4*)(bsrc + 8);

    for (int k0 = 0; k0 < CDIM; k0 += 32) {
        __syncthreads();
        *(uint4*)&As[sr][sq] = apre;
        *(uint4*)&Bs[srB][sqB] = bp0;
        *(uint4*)&Bs[srB][sqB + 8] = bp1;
        __syncthreads();

        if (k0 + 32 < CDIM) {
            if (ar >= 0) apre = *(const uint4*)(asrc + k0 + 32);
            bp0 = *(const uint4*)(bsrc + k0 + 32);
            bp1 = *(const uint4*)(bsrc + k0 + 40);
        }

        s16x8 af0 = *(const s16x8*)&As[wr * 32 + l15][lk];
        s16x8 af1 = *(const s16x8*)&As[wr * 32 + 16 + l15][lk];
#pragma unroll
        for (int j = 0; j < 4; ++j) {
            s16x8 bf = *(const s16x8*)&Bs[wc * 64 + j * 16 + l15][lk];
            acc[0][j] = __builtin_amdgcn_mfma_f32_16x16x32_bf16(af0, bf, acc[0][j], 0, 0, 0);
            acc[1][j] = __builtin_amdgcn_mfma_f32_16x16x32_bf16(af1, bf, acc[1][j], 0, 0, 0);
        }
    }

    int rbase = wr * 32 + (lane >> 4) * 4;
#pragma unroll
    for (int mi = 0; mi < 2; ++mi) {
#pragma unroll
        for (int r = 0; r < 4; ++r) {
            int node = ridx[rbase + mi * 16 + r];
            if (node < 0) continue;
            size_t b0 = (size_t)node * ostr + oc0 + wc * 64 + l15;
#pragma unroll
            for (int j = 0; j < 4; ++j)
                out[b0 + j * 16] = f2b(acc[mi][j][r]);
        }
    }
}

// ================= out GEMM v7: out = svn @ af_b (K=1280), 64x64 tiles =================
// XCD-grouped, dbuf LDS for BOTH A and B, one barrier per 64-k chunk.
// B staged coalesced (one full 128B line per row per chunk) -> kills the 16-way
// per-lane row-gather that saturated the address pipe in v5/v6.
__global__ __launch_bounds__(256) void outgemm_k(
    const u16* __restrict__ svn, const u16* __restrict__ af_b, float* __restrict__ out,
    const int* __restrict__ perm, const int* __restrict__ off, int N, int bpt, int npanel,
    const float* __restrict__ x, const float* __restrict__ skip)
{
    __shared__ u16 As[2][64][68];
    __shared__ u16 Bs[2][64][68];
    __shared__ int ridx[64];

    int bid = blockIdx.x;
    int xcd = bid & 7;
    int rr_ = bid >> 3;
    int g = rr_ / 4, cx = rr_ % 4;
    int p = g * 8 + xcd;
    if (p >= npanel) return;
    int t = p / bpt, bi = p % bpt;
    int i0 = off[t] + bi * 64, iend = off[t + 1];
    if (i0 >= iend) return;
    int tid = threadIdx.x;
    if (tid < 64) ridx[tid] = (i0 + tid < iend) ? perm[i0 + tid] : -1;
    __syncthreads();

    int lane = tid & 63, y = tid >> 6;     // wave y owns out cols cx*64 + y*16 .. +16
    int l15 = lane & 15, lq = lane >> 4;
    int lk = lq * 8;
    int colb = cx * 64 + y * 16;

    int sr = tid >> 2, sc = (tid & 3) * 16;
    int ar = ridx[sr];
    const u16* asrc = svn + (size_t)(ar < 0 ? 0 : ar) * QWC + sc;
    const u16* bsrc = af_b + ((size_t)t * CDIM + cx * 64 + sr) * QWC + sc;

    f32x4 acc[4];
#pragma unroll
    for (int mi = 0; mi < 4; ++mi) acc[mi] = (f32x4){0.f, 0.f, 0.f, 0.f};

    uint4 a0 = make_uint4(0, 0, 0, 0), a1 = make_uint4(0, 0, 0, 0);
    if (ar >= 0) {
        a0 = *(const uint4*)(asrc);
        a1 = *(const uint4*)(asrc + 8);
    }
    uint4 b0 = *(const uint4*)(bsrc);
    uint4 b1 = *(const uint4*)(bsrc + 8);
    *(uint4*)&As[0][sr][sc] = a0;
    *(uint4*)&As[0][sr][sc + 8] = a1;
    *(uint4*)&Bs[0][sr][sc] = b0;
    *(uint4*)&Bs[0][sr][sc + 8] = b1;

    for (int kc = 0; kc < 20; ++kc) {
        int cur = kc & 1;
        if (kc + 1 < 20) {
            int ko = (kc + 1) * 64;
            if (ar >= 0) {
                a0 = *(const uint4*)(asrc + ko);
                a1 = *(const uint4*)(asrc + ko + 8);
            }
            b0 = *(const uint4*)(bsrc + ko);
            b1 = *(const uint4*)(bsrc + ko + 8);
        }
        __syncthreads();   // [cur] writes (prev iter) complete; prev reads of [cur^1] done

        s16x8 bf0 = *(const s16x8*)&Bs[cur][y * 16 + l15][lk];
        s16x8 bf1 = *(const s16x8*)&Bs[cur][y * 16 + l15][32 + lk];
#pragma unroll
        for (int mi = 0; mi < 4; ++mi) {
            s16x8 af0 = *(const s16x8*)&As[cur][mi * 16 + l15][lk];
            s16x8 af1 = *(const s16x8*)&As[cur][mi * 16 + l15][32 + lk];
            acc[mi] = __builtin_amdgcn_mfma_f32_16x16x32_bf16(af0, bf0, acc[mi], 0, 0, 0);
            acc[mi] = __builtin_amdgcn_mfma_f32_16x16x32_bf16(af1, bf1, acc[mi], 0, 0, 0);
        }

        if (kc + 1 < 20) {
            *(uint4*)&As[cur ^ 1][sr][sc] = a0;
            *(uint4*)&As[cur ^ 1][sr][sc + 8] = a1;
            *(uint4*)&Bs[cur ^ 1][sr][sc] = b0;
            *(uint4*)&Bs[cur ^ 1][sr][sc + 8] = b1;
        }
    }

    float alpha = 1.f / (1.f + __expf(-skip[t]));
    float beta = 1.f - alpha;
#pragma unroll
    for (int mi = 0; mi < 4; ++mi) {
#pragma unroll
        for (int r = 0; r < 4; ++r) {
            int node = ridx[mi * 16 + lq * 4 + r];
            if (node < 0) continue;
            size_t b0o = (size_t)node * CDIM + colb + l15;
            out[b0o] = acc[mi][r] * alpha + x[b0o] * beta;
        }
    }
}

// ================= gather v3: one wave per dst; single merged edge loop (sorted by et),
// 2-deep prefetch, uniform-branch segment transitions, svn in-place over qw ============
__global__ __launch_bounds__(256) void gather3_k(
    const u16* __restrict__ kb, const u16* __restrict__ vb, u16* __restrict__ qwsv,
    const float* __restrict__ pri, const int* __restrict__ rowptr, const int* __restrict__ epay,
    int N)
{
    int d = (blockIdx.x * 256 + threadIdx.x) >> 6;
    if (d >= N) return;
    int lane = threadIdx.x & 63, h = lane >> 3;
    const float rsD = 0.17677669529663687f;
    size_t rowb = (size_t)d * QWC + lane * 4;

    ushort4 qu0 = *(const ushort4*)(qwsv + rowb);
    ushort4 qu1 = *(const ushort4*)(qwsv + rowb + 256);
    ushort4 qu2 = *(const ushort4*)(qwsv + rowb + 512);
    ushort4 qu3 = *(const ushort4*)(qwsv + rowb + 768);
    ushort4 qu4 = *(const ushort4*)(qwsv + rowb + 1024);

    int p0 = __builtin_amdgcn_readfirstlane(rowptr[d * ET]);
    int p1 = __builtin_amdgcn_readfirstlane(rowptr[d * ET + ET]);

    float Sv0[4] = {0,0,0,0}, Sv1[4] = {0,0,0,0}, Sv2[4] = {0,0,0,0};
    float Sv3[4] = {0,0,0,0}, Sv4[4] = {0,0,0,0};
    float a0 = 0.f, a1 = 0.f, a2 = 0.f, a3 = 0.f, dsum = 0.f;
    int cur_et = -1;
    float cq0 = 0.f, cq1 = 0.f, cq2 = 0.f, cq3 = 0.f, cpf = 0.f;

    int payc = 0; ushort4 kuc = {0,0,0,0}, vuc = {0,0,0,0};
    if (p0 < p1) {
        payc = epay[p0];
        int s = payc & 0xFFFFFF;
        kuc = *(const ushort4*)(kb + (size_t)s * CDIM + lane * 4);
        vuc = *(const ushort4*)(vb + (size_t)s * CDIM + lane * 4);
    }

    for (int p = p0; p < p1; ++p) {
        int payn = 0; ushort4 kun = {0,0,0,0}, vun = {0,0,0,0};
        if (p + 1 < p1) {
            payn = epay[p + 1];
            int sn = payn & 0xFFFFFF;
            kun = *(const ushort4*)(kb + (size_t)sn * CDIM + lane * 4);
            vun = *(const ushort4*)(vb + (size_t)sn * CDIM + lane * 4);
        }
        int et = __builtin_amdgcn_readfirstlane(payc) >> 24;
        if (et != cur_et) {
            switch (cur_et) {
                case 0: Sv0[0]=a0; Sv0[1]=a1; Sv0[2]=a2; Sv0[3]=a3; break;
                case 1: Sv1[0]=a0; Sv1[1]=a1; Sv1[2]=a2; Sv1[3]=a3; break;
                case 2: Sv2[0]=a0; Sv2[1]=a1; Sv2[2]=a2; Sv2[3]=a3; break;
                case 3: Sv3[0]=a0; Sv3[1]=a1; Sv3[2]=a2; Sv3[3]=a3; break;
                default: break;
            }
            a0 = a1 = a2 = a3 = 0.f;
            cur_et = et;
            ushort4 q = (et == 0) ? qu0 : (et == 1) ? qu1 : (et == 2) ? qu2
                       : (et == 3) ? qu3 : qu4;
            cq0 = b2f(q.x); cq1 = b2f(q.y); cq2 = b2f(q.z); cq3 = b2f(q.w);
            cpf = pri[et * HD + h] * rsD;
        }
        float t = b2f(kuc.x) * cq0 + b2f(kuc.y) * cq1 + b2f(kuc.z) * cq2 + b2f(kuc.w) * cq3;
        t += __shfl_xor(t, 1, 8);
        t += __shfl_xor(t, 2, 8);
        t += __shfl_xor(t, 4, 8);
        float ex = __expf(t * cpf);
        a0 += ex * b2f(vuc.x); a1 += ex * b2f(vuc.y);
        a2 += ex * b2f(vuc.z); a3 += ex * b2f(vuc.w);
        dsum += ex;
        payc = payn; kuc = kun; vuc = vun;
    }
    switch (cur_et) {
        case 0: Sv0[0]=a0; Sv0[1]=a1; Sv0[2]=a2; Sv0[3]=a3; break;
        case 1: Sv1[0]=a0; Sv1[1]=a1; Sv1[2]=a2; Sv1[3]=a3; break;
        case 2: Sv2[0]=a0; Sv2[1]=a1; Sv2[2]=a2; Sv2[3]=a3; break;
        case 3: Sv3[0]=a0; Sv3[1]=a1; Sv3[2]=a2; Sv3[3]=a3; break;
        case 4: Sv4[0]=a0; Sv4[1]=a1; Sv4[2]=a2; Sv4[3]=a3; break;
        default: break;
    }

    float inv = dsum > 0.f ? 1.f / dsum : 0.f;
    ushort4 o;
    o.x=f2b(Sv0[0]*inv); o.y=f2b(Sv0[1]*inv); o.z=f2b(Sv0[2]*inv); o.w=f2b(Sv0[3]*inv);
    *(ushort4*)(qwsv + rowb) = o;
    o.x=f2b(Sv1[0]*inv); o.y=f2b(Sv1[1]*inv); o.z=f2b(Sv1[2]*inv); o.w=f2b(Sv1[3]*inv);
    *(ushort4*)(qwsv + rowb + 256) = o;
    o.x=f2b(Sv2[0]*inv); o.y=f2b(Sv2[1]*inv); o.z=f2b(Sv2[2]*inv); o.w=f2b(Sv2[3]*inv);
    *(ushort4*)(qwsv + rowb + 512) = o;
    o.x=f2b(Sv3[0]*inv); o.y=f2b(Sv3[1]*inv); o.z=f2b(Sv3[2]*inv); o.w=f2b(Sv3[3]*inv);
    *(ushort4*)(qwsv + rowb + 768) = o;
    o.x=f2b(Sv4[0]*inv); o.y=f2b(Sv4[1]*inv); o.z=f2b(Sv4[2]*inv); o.w=f2b(Sv4[3]*inv);
    *(ushort4*)(qwsv + rowb + 1024) = o;
}

// ================= launch =================
extern "C" void kernel_launch(void* const* d_in, const int* in_sizes, int n_in,
                              void* d_out, int out_size, void* d_ws, size_t ws_size,
                              hipStream_t stream) {
    const float* x    = (const float*)d_in[0];
    const float* Wk   = (const float*)d_in[1];
    const float* Wq   = (const float*)d_in[2];
    const float* Wv   = (const float*)d_in[3];
    const float* Ratt = (const float*)d_in[4];
    const float* Rmsg = (const float*)d_in[5];
    const float* pri  = (const float*)d_in[6];
    const float* Wa   = (const float*)d_in[7];
    const float* skip = (const float*)d_in[8];
    const int* src   = (const int*)d_in[9];
    const int* dst   = (const int*)d_in[10];
    const int* etype = (const int*)d_in[11];
    const int* ntype = (const int*)d_in[12];

    int N = in_sizes[12];
    int E = in_sizes[9];
    const size_t NC = (size_t)N * CDIM;
    const int KEYS = N * ET;
    const int NB = (KEYS + 255) / 256;
    const int nblk = (N + 255) / 256;
    const size_t WTE = (size_t)NT * CDIM * CDIM;       // per weight tensor (u16 elems)
    const size_t QFE = (size_t)NT * QWC * CDIM;        // folded tensors (u16 elems)

    // ---- workspace (~190 MB) ----
    u16* kb   = (u16*)d_ws;                  // NC
    u16* vb   = kb + NC;                     // NC
    u16* qwsv = vb + NC;                     // 5*NC (qw then svn, in-place)
    u16* wtb  = qwsv + 5 * NC;               // 2*WTE (Wk, Wv transposed bf16)
    u16* qf_b = wtb + 2 * WTE;               // QFE
    u16* af_b = qf_b + QFE;                  // QFE
    int* rowptr = (int*)(af_b + QFE);        // KEYS+1  (persistent)
    int* perm   = rowptr + KEYS + 1;         // N       (persistent)
    int* epay   = perm + N;                  // E       (persistent)
    int* off    = epay + E;                  // NT+1    (persistent)
    // setup-only ints aliased into qwsv (dead before the projection GEMM writes it)
    int* khist = (int*)qwsv;                 // KEYS (zeroed)
    int* kscan = khist + KEYS;               // KEYS
    int* bsum  = kscan + KEYS;               // 1024
    int* bcnt  = bsum + 1024;                // NT*nblk
    int* base  = bcnt + NT * nblk;           // NT*nblk

    // xb (bf16 copy of x) lives in d_out scratch: NC u16 = half of out bytes;
    // fully dead before outgemm_k overwrites d_out.
    u16* xb = (u16*)d_out;

    hipMemsetAsync(khist, 0, (size_t)KEYS * sizeof(int), stream);

    // node buckets (atomic-free, stable)
    bhist_k<<<nblk, 256, 0, stream>>>(ntype, N, nblk, bcnt);
    bscan_k<<<1, 1024, 0, stream>>>(bcnt, base, off, NT * nblk, nblk, N);
    bscatter_k<<<nblk, 256, 0, stream>>>(ntype, N, nblk, base, perm);

    // edge counting sort by (dst, etype) -> CSR (epay packs et<<24 | src)
    ehist_k<<<(E + 255) / 256, 256, 0, stream>>>(dst, etype, E, khist);
    kscan1_k<<<NB, 256, 0, stream>>>(khist, kscan, bsum, KEYS);
    kscan2_k<<<1, 1024, 0, stream>>>(bsum, NB);
    kscan3r_k<<<NB, 256, 0, stream>>>(kscan, bsum, rowptr, KEYS, E);
    escatter_k<<<(E + 255) / 256, 256, 0, stream>>>(src, dst, etype, E, kscan, epay);

    // weight prep + x -> bf16
    wconv2_k<<<dim3(4, 4, 2 * NT), 256, 0, stream>>>(Wk, Wv, wtb);
    rfold_k<<<dim3(NT * ET * HD, 2), 256, 0, stream>>>(Wq, Ratt, qf_b, Wa, Rmsg, af_b);
    size_t n4 = NC / 4;
    f2bv_k<<<(int)((n4 + 255) / 256), 256, 0, stream>>>(x, xb, n4);

    int bpt = (N + 63) / 64;
    int npanel = NT * bpt;
    int ppad = (npanel + 7) & ~7;

    // fused k|v|qw projection, XCD-grouped, 64x128 tiles (14 per panel)
    gemmall_k<<<ppad * 14, 256, 0, stream>>>(xb, wtb, qf_b, kb, vb, qwsv,
                                             perm, off, N, bpt, npanel);

    // edge gather: merged loop, prefetch; svn (normalized) in-place over qw
    gather3_k<<<(N * 64 + 255) / 256, 256, 0, stream>>>(kb, vb, qwsv, pri, rowptr, epay, N);

    // out = svn @ (Rmsg*Wa), sigmoid-gated skip; dbuf A+B LDS, one barrier/chunk
    outgemm_k<<<ppad * 4, 256, 0, stream>>>(qwsv, af_b, (float*)d_out, perm, off, N, bpt,
                                            npanel, x, skip);
}